// Round 8
// baseline (428.855 us; speedup 1.0000x reference)
//
#include <hip/hip_runtime.h>
#include <hip/hip_bf16.h>
#include <math.h>

// Problem constants
#define B_    8
#define CDIM  512
#define HW    4096
#define CI_   64
#define MT    64            // kv rows per tile
#define NTIL  (HW/MT)       // 64 tiles
#define KROW  72            // LDS row stride (u16): 144B -> conflict-free b128
#define VROW  72
#define GROW  68            // gemm LDS row stride (u16): 136B -> uniform b128 bank spread

typedef __attribute__((ext_vector_type(8))) short bf16x8;
typedef __attribute__((ext_vector_type(4))) float f32x4;
typedef __attribute__((ext_vector_type(16))) float f32x16;
typedef unsigned short u16;
typedef unsigned int   u32;

union fragu { bf16x8 v; u32 w[4]; };

// fp32 -> bf16 bits with RNE rounding
__device__ __forceinline__ u32 bfr(float f) {
  u32 x = __float_as_uint(f);
  return (x + 0x7fffu + ((x >> 16) & 1u)) >> 16;
}
// packed 2xf32 -> bf16x2 (RNE) via HW instruction
__device__ __forceinline__ u32 cvtpk(float a, float b) {
  u32 r;
  asm("v_cvt_pk_bf16_f32 %0, %1, %2" : "=v"(r) : "v"(a), "v"(b));
  return r;
}

// ---------------- cast fp32 -> bf16 (weights) ----------------
__global__ void cast_bf16(const float* __restrict__ in, u16* __restrict__ out, int n) {
  int i = blockIdx.x * 256 + threadIdx.x;
  if (i < n) out[i] = (u16)bfr(in[i]);
}

// ---------------- transpose+cast: X [C,HW] f32 -> Xt [HW,C] bf16, per batch ----------------
__global__ void transpose_cast(const float* __restrict__ X, u16* __restrict__ Xt) {
  __shared__ float tile[32][33];
  const int n0 = blockIdx.x * 32, c0 = blockIdx.y * 32;
  const float* Xb = X + (size_t)blockIdx.z * CDIM * HW;
  u16* Xtb = Xt + (size_t)blockIdx.z * HW * CDIM;
  const int tx = threadIdx.x, ty = threadIdx.y; // block (32,8)
#pragma unroll
  for (int i = 0; i < 4; ++i)
    tile[ty + 8 * i][tx] = Xb[(size_t)(c0 + ty + 8 * i) * HW + n0 + tx];
  __syncthreads();
#pragma unroll
  for (int i = 0; i < 4; ++i)
    Xtb[(size_t)(n0 + ty + 8 * i) * CDIM + c0 + tx] = (u16)bfr(tile[tx][ty + 8 * i]);
}

// ---------------- NT GEMM (LDS-staged): D[i,j] = (sum_k A[i,k]*B[j,k] + bias)*alpha ----------------
// BM=128, BN=64, BK=64. 4 waves; wave = 32i x 64j. Reg->LDS double-buffered
// staging with coalesced uint4 loads issued one K-step ahead (R4/R7 pattern).
// Padded rows (GROW=68 u16 = 136B == 2 mod 32 words) -> uniform b128 bank spread.
__global__ __launch_bounds__(256) void gemm_nt(
    const u16* __restrict__ A, const u16* __restrict__ Bm, u16* __restrict__ D,
    const float* __restrict__ bias, int biasRow, float alpha,
    int lda, int ldb, int ldd, long aBatch, long bBatch, long dBatch, int Kd)
{
  __shared__ u16 As[2][128 * GROW];   // 2 x 17.0 KB
  __shared__ u16 Bs[2][64 * GROW];    // 2 x  8.5 KB

  const int tid = threadIdx.x, wid = tid >> 6, lane = tid & 63;
  const int l31 = lane & 31, h = lane >> 5;
  const int i0 = blockIdx.x * 128;
  const int j0 = blockIdx.y * 64;
  const u16* Ab = A + blockIdx.z * aBatch + (size_t)i0 * lda;
  const u16* Bb = Bm + blockIdx.z * bBatch + (size_t)j0 * ldb;

  // staging maps: A 128 rows x 128B (2 thr/row, 64B each); B 64 rows (4 thr/row, 32B each)
  const int arow = tid >> 1, acol = (tid & 1) * 32;
  const int brow = tid >> 2, bcol = (tid & 3) * 16;
  uint4 ar[4], br[2];

#define GLOAD(T) do { \
    const u16* _a = Ab + (size_t)arow * lda + (T) * 64 + acol; \
    _Pragma("unroll") \
    for (int j = 0; j < 4; ++j) ar[j] = *(const uint4*)(_a + j * 8); \
    const u16* _b = Bb + (size_t)brow * ldb + (T) * 64 + bcol; \
    _Pragma("unroll") \
    for (int j = 0; j < 2; ++j) br[j] = *(const uint4*)(_b + j * 8); \
  } while (0)

#define GWRITE(BUF) do { \
    _Pragma("unroll") \
    for (int j = 0; j < 4; ++j) *(uint4*)(&As[BUF][arow * GROW + acol + j * 8]) = ar[j]; \
    _Pragma("unroll") \
    for (int j = 0; j < 2; ++j) *(uint4*)(&Bs[BUF][brow * GROW + bcol + j * 8]) = br[j]; \
  } while (0)

  f32x16 acc[2];
#pragma unroll
  for (int jt = 0; jt < 2; ++jt)
#pragma unroll
    for (int i = 0; i < 16; ++i) acc[jt][i] = 0.f;

  const int nk = Kd >> 6;
  GLOAD(0); GWRITE(0);
  __syncthreads();

  for (int t = 0; t < nk; ++t) {
    const int par = t & 1;
    if (t + 1 < nk) GLOAD(t + 1);

    bf16x8 af[4], bf[2][4];
#pragma unroll
    for (int kk = 0; kk < 4; ++kk)
      af[kk] = *(const bf16x8*)(&As[par][(wid * 32 + l31) * GROW + kk * 16 + h * 8]);
#pragma unroll
    for (int jt = 0; jt < 2; ++jt)
#pragma unroll
      for (int kk = 0; kk < 4; ++kk)
        bf[jt][kk] = *(const bf16x8*)(&Bs[par][(jt * 32 + l31) * GROW + kk * 16 + h * 8]);

#pragma unroll
    for (int kk = 0; kk < 4; ++kk)
#pragma unroll
      for (int jt = 0; jt < 2; ++jt)
        acc[jt] = __builtin_amdgcn_mfma_f32_32x32x16_bf16(af[kk], bf[jt][kk], acc[jt], 0, 0, 0);

    if (t + 1 < nk) GWRITE((t + 1) & 1);
    __syncthreads();
  }

  u16* Db = D + blockIdx.z * dBatch;
#pragma unroll
  for (int jt = 0; jt < 2; ++jt)
#pragma unroll
    for (int r = 0; r < 16; ++r) {
      int i = i0 + wid * 32 + (r & 3) + 8 * (r >> 2) + 4 * h;   // D row (reg-mapped)
      int j = j0 + jt * 32 + l31;                               // D col (lane)
      float v = (acc[jt][r] + (biasRow ? bias[i] : bias[j])) * alpha;
      Db[(size_t)i * ldd + j] = (u16)bfr(v);
    }
}

// ---------------- fused flash attention + gamma*attn + value ----------------
// R7 kernel, byte-identical (measured 240us, MfmaUtil 38%, no spill).
__global__ __launch_bounds__(256, 2) void flash_attn(
    const u16* __restrict__ Q, const u16* __restrict__ K, const u16* __restrict__ V,
    const float* __restrict__ value, const float* __restrict__ gammap, float* __restrict__ out)
{
  __shared__ u16 Ks[2][64 * KROW];    // 2 x 9.2 KB  [m=64][ci=64 +pad]
  __shared__ u16 Vs[2][128 * VROW];   // 2 x 18.4 KB [c=128][m=64 +pad]

  const int b  = blockIdx.x & 7;
  const int rb = (blockIdx.x >> 3) & 15;
  const int ch = blockIdx.x >> 7;
  const int tid = threadIdx.x, wid = tid >> 6, lane = tid & 63;
  const int l31 = lane & 31, h = lane >> 5;

  const int n0 = rb * 256 + wid * 64;   // wave q-row base
  const int c0 = ch * 128;              // block c base

  const u16* Qb = Q + (size_t)b * HW * CI_;
  const u16* Kb = K + (size_t)b * HW * CI_;
  const u16* Vb = V + (size_t)b * CDIM * HW + (size_t)c0 * HW;

  // Q B-frags: col n = n0 + ng*32 + l31, k = kk*16 + h*8 + j
  bf16x8 qf[2][4];
#pragma unroll
  for (int ng = 0; ng < 2; ++ng)
#pragma unroll
    for (int kk = 0; kk < 4; ++kk)
      qf[ng][kk] = *(const bf16x8*)(Qb + (size_t)(n0 + ng * 32 + l31) * CI_ + kk * 16 + h * 8);

  f32x16 acc[2][4];
#pragma unroll
  for (int ng = 0; ng < 2; ++ng)
#pragma unroll
    for (int ct = 0; ct < 4; ++ct)
#pragma unroll
      for (int i = 0; i < 16; ++i) acc[ng][ct][i] = 0.f;
  float lp0 = 0.f, lp1 = 0.f;

  // staging maps: K tile 8KB (4 thr/row x 2 b128), V tile 16KB (2 thr/row x 4 b128)
  const int krow_ = tid >> 2, kcol = (tid & 3) * 8;
  const int vrow_ = tid >> 1, vcol = (tid & 1) * 32;
  uint4 kr[2], vr[4];

#define SISSUE(T) do { \
    const u16* kp_ = Kb + (size_t)((T) * MT + krow_) * CI_ + kcol; \
    kr[0] = *(const uint4*)kp_; \
    kr[1] = *(const uint4*)(kp_ + 32); \
    const u16* vp_ = Vb + (size_t)vrow_ * HW + (T) * MT + vcol; \
    _Pragma("unroll") \
    for (int j = 0; j < 4; ++j) vr[j] = *(const uint4*)(vp_ + j * 8); \
  } while (0)

#define SWRITE(BUF) do { \
    *(uint4*)(&Ks[BUF][krow_ * KROW + kcol]) = kr[0]; \
    *(uint4*)(&Ks[BUF][krow_ * KROW + kcol + 32]) = kr[1]; \
    _Pragma("unroll") \
    for (int j = 0; j < 4; ++j) \
      *(uint4*)(&Vs[BUF][vrow_ * VROW + vcol + j * 8]) = vr[j]; \
  } while (0)

  SISSUE(0); SWRITE(0);
  __syncthreads();

  for (int t = 0; t < NTIL; ++t) {
    const int par = t & 1;
    if (t + 1 < NTIL) SISSUE(t + 1);   // next-tile global loads; land during compute

#pragma unroll
    for (int s = 0; s < 2; ++s) {      // m-strip of 32 within the 64-m tile
      // K A-frags: row m = s*32 + l31, k = kk*16 + h*8 + j
      bf16x8 kf[4];
#pragma unroll
      for (int kk = 0; kk < 4; ++kk)
        kf[kk] = *(const bf16x8*)(&Ks[par][(s * 32 + l31) * KROW + kk * 16 + h * 8]);

      bf16x8 pa[2][2];                 // [ng][kk-local] PV B-frags for this strip
#pragma unroll
      for (int ng = 0; ng < 2; ++ng) {
        f32x16 st;
#pragma unroll
        for (int i = 0; i < 16; ++i) st[i] = 0.f;
#pragma unroll
        for (int kk = 0; kk < 4; ++kk)
          st = __builtin_amdgcn_mfma_f32_32x32x16_bf16(kf[kk], qf[ng][kk], st, 0, 0, 0);

        // exp + row-sum partial (lane holds 16 of 32 m-values for row n=l31)
        float p[16]; float rs = 0.f;
#pragma unroll
        for (int r = 0; r < 16; ++r) { p[r] = __expf(st[r]); rs += p[r]; }
        if (ng == 0) lp0 += rs; else lp1 += rs;

        // T12 pack: quads m(r) = (r&3) + 8*(r>>2) + 4h (within strip)
        u32 qa0 = cvtpk(p[0],  p[1]),  qa1 = cvtpk(p[2],  p[3]);   // m 4h+0..3
        u32 qb0 = cvtpk(p[4],  p[5]),  qb1 = cvtpk(p[6],  p[7]);   // m 8+4h+0..3
        u32 qc0 = cvtpk(p[8],  p[9]),  qc1 = cvtpk(p[10], p[11]);  // m 16+4h+0..3
        u32 qd0 = cvtpk(p[12], p[13]), qd1 = cvtpk(p[14], p[15]);  // m 24+4h+0..3
        // in-place half swap: h=0 ends {own qa, partner qa} = m0..7; h=1 {partner qb, own qb} = m8..15
        asm("v_permlane32_swap_b32 %0, %1" : "+v"(qa0), "+v"(qb0));
        asm("v_permlane32_swap_b32 %0, %1" : "+v"(qa1), "+v"(qb1));
        asm("v_permlane32_swap_b32 %0, %1" : "+v"(qc0), "+v"(qd0));
        asm("v_permlane32_swap_b32 %0, %1" : "+v"(qc1), "+v"(qd1));
        fragu f0; f0.w[0] = qa0; f0.w[1] = qa1; f0.w[2] = qb0; f0.w[3] = qb1;
        pa[ng][0] = f0.v;
        fragu f1; f1.w[0] = qc0; f1.w[1] = qc1; f1.w[2] = qd0; f1.w[3] = qd1;
        pa[ng][1] = f1.v;
      }

      // PV partial for this strip: kk = 2s + kkl
      __builtin_amdgcn_s_setprio(1);
#pragma unroll
      for (int ct = 0; ct < 4; ++ct)
#pragma unroll
        for (int kkl = 0; kkl < 2; ++kkl) {
          bf16x8 vf = *(const bf16x8*)(&Vs[par][(ct * 32 + l31) * VROW + (2 * s + kkl) * 16 + h * 8]);
          acc[0][ct] = __builtin_amdgcn_mfma_f32_32x32x16_bf16(vf, pa[0][kkl], acc[0][ct], 0, 0, 0);
          acc[1][ct] = __builtin_amdgcn_mfma_f32_32x32x16_bf16(vf, pa[1][kkl], acc[1][ct], 0, 0, 0);
        }
      __builtin_amdgcn_s_setprio(0);
    }

    if (t + 1 < NTIL) SWRITE((t + 1) & 1);
    __syncthreads();   // single barrier: protects dbuf parity both directions
  }

  // ---- epilogue: per-wave LDS transpose so value/out stay coalesced ----
  __syncthreads();   // everyone done with Ks/Vs; reuse as scratch
  float* Tls = (float*)((char*)&Vs[0][0] + wid * 4352);  // 32c x 33n f32 = 4224B per wave
  const float g = gammap[0];
  const float ls0 = lp0 + __shfl_xor(lp0, 32);
  const float ls1 = lp1 + __shfl_xor(lp1, 32);
  const float ri0 = g / ls0, ri1 = g / ls1;   // gamma folded; lane's n = l31 (per ng)
  const size_t obase = (size_t)b * CDIM * HW;
#pragma unroll
  for (int ng = 0; ng < 2; ++ng) {
    const float ri = ng ? ri1 : ri0;
#pragma unroll
    for (int ct = 0; ct < 4; ++ct) {
      // write: Tls[c_local][n_local]
#pragma unroll
      for (int r = 0; r < 16; ++r) {
        int cc = (r & 3) + 8 * (r >> 2) + 4 * h;
        Tls[cc * 33 + l31] = acc[ng][ct][r] * ri;
      }
      // read coalesced: lane -> c = l31, n = 2p + h
#pragma unroll
      for (int p = 0; p < 16; ++p) {
        float v = Tls[l31 * 33 + 2 * p + h];
        int n = n0 + ng * 32 + 2 * p + h;
        int c = c0 + ct * 32 + l31;
        size_t idx = obase + (size_t)n * CDIM + c;
        out[idx] = v + value[idx];
      }
    }
  }
}

extern "C" void kernel_launch(void* const* d_in, const int* in_sizes, int n_in,
                              void* d_out, int out_size, void* d_ws, size_t ws_size,
                              hipStream_t stream) {
  const float* query = (const float*)d_in[0];
  const float* key   = (const float*)d_in[1];
  const float* value = (const float*)d_in[2];
  const float* Wq    = (const float*)d_in[3];
  const float* bq    = (const float*)d_in[4];
  const float* Wk    = (const float*)d_in[5];
  const float* bk    = (const float*)d_in[6];
  const float* Wv    = (const float*)d_in[7];
  const float* bv    = (const float*)d_in[8];
  const float* gamma = (const float*)d_in[9];

  char* ws = (char*)d_ws;
  u16* XT  = (u16*)(ws);               // 33,554,432 B  [B,HW,C] bf16
  u16* Qb  = (u16*)(ws + 33554432);    //  4,194,304 B  [B,HW,CI]
  u16* Kb  = (u16*)(ws + 37748736);    //  4,194,304 B  [B,HW,CI]
  u16* Vb  = (u16*)(ws + 41943040);    // 33,554,432 B  [B,C,HW]
  u16* WQb = (u16*)(ws + 75497472);    //     65,536 B
  u16* WKb = (u16*)(ws + 75563008);    //     65,536 B
  u16* WVb = (u16*)(ws + 75628544);    //    524,288 B

  cast_bf16<<<(32768 + 255) / 256, 256, 0, stream>>>(Wq, WQb, 32768);
  cast_bf16<<<(32768 + 255) / 256, 256, 0, stream>>>(Wk, WKb, 32768);
  cast_bf16<<<(262144 + 255) / 256, 256, 0, stream>>>(Wv, WVb, 262144);

  dim3 tgrid(HW / 32, CDIM / 32, B_);
  dim3 tblk(32, 8);

  // Q = (query^T Wq^T + bq) * (1/8)   -> [B,HW,CI]
  transpose_cast<<<tgrid, tblk, 0, stream>>>(query, XT);
  gemm_nt<<<dim3(HW / 128, 1, B_), 256, 0, stream>>>(
      XT, WQb, Qb, bq, 0, 0.125f, CDIM, CDIM, CI_,
      (long)HW * CDIM, 0L, (long)HW * CI_, CDIM);

  // K = key^T Wk^T + bk               -> [B,HW,CI]
  transpose_cast<<<tgrid, tblk, 0, stream>>>(key, XT);
  gemm_nt<<<dim3(HW / 128, 1, B_), 256, 0, stream>>>(
      XT, WKb, Kb, bk, 0, 1.0f, CDIM, CDIM, CI_,
      (long)HW * CDIM, 0L, (long)HW * CI_, CDIM);

  // V^T = Wv (value^T)^T + bv  stored [B, C, HW]
  transpose_cast<<<tgrid, tblk, 0, stream>>>(value, XT);
  gemm_nt<<<dim3(CDIM / 128, HW / 64, B_), 256, 0, stream>>>(
      WVb, XT, Vb, bv, 1, 1.0f, CDIM, CDIM, HW,
      0L, (long)HW * CDIM, (long)CDIM * HW, CDIM);

  // Fused flash attention + epilogue
  flash_attn<<<512, 256, 0, stream>>>(Qb, Kb, Vb, value, gamma, (float*)d_out);
}

// Round 9
// 397.730 us; speedup vs baseline: 1.0783x; 1.0783x over previous
//
#include <hip/hip_runtime.h>
#include <hip/hip_bf16.h>
#include <math.h>

// Problem constants
#define B_    8
#define CDIM  512
#define HW    4096
#define CI_   64
#define MT    64            // kv rows per tile
#define NTIL  (HW/MT)       // 64 tiles
#define KROW  72            // LDS row stride (u16): 144B -> conflict-free b128
#define VROW  72

typedef __attribute__((ext_vector_type(8))) short bf16x8;
typedef __attribute__((ext_vector_type(4))) float f32x4;
typedef __attribute__((ext_vector_type(16))) float f32x16;
typedef unsigned short u16;
typedef unsigned int   u32;

union fragu { bf16x8 v; u32 w[4]; };

// fp32 -> bf16 bits with RNE rounding
__device__ __forceinline__ u32 bfr(float f) {
  u32 x = __float_as_uint(f);
  return (x + 0x7fffu + ((x >> 16) & 1u)) >> 16;
}
// packed 2xf32 -> bf16x2 (RNE) via HW instruction
__device__ __forceinline__ u32 cvtpk(float a, float b) {
  u32 r;
  asm("v_cvt_pk_bf16_f32 %0, %1, %2" : "=v"(r) : "v"(a), "v"(b));
  return r;
}

// ---------------- fused cast fp32 -> bf16 for the three weight tensors ----------------
__global__ void cast3(const float* __restrict__ wq, const float* __restrict__ wk,
                      const float* __restrict__ wv, u16* __restrict__ oq,
                      u16* __restrict__ ok, u16* __restrict__ ov) {
  int i = blockIdx.x * 256 + threadIdx.x;
  if (i < CI_ * CDIM) { oq[i] = (u16)bfr(wq[i]); ok[i] = (u16)bfr(wk[i]); }
  ov[i] = (u16)bfr(wv[i]);   // grid sized to CDIM*CDIM
}

// ---------------- transpose+cast x2: X [C,HW] f32 -> T [HW,C] bf16 ----------------
// 64x64 tiles, block (64,4). z < zsplit -> (Xa,Ta) else (Xb,Tb). Full-width 128B stores.
__global__ void transpose_cast2(const float* __restrict__ Xa, const float* __restrict__ Xb_,
                                u16* __restrict__ Ta, u16* __restrict__ Tb, int zsplit) {
  __shared__ float tile[64][65];
  const int z = blockIdx.z;
  const float* X = (z < zsplit) ? Xa : Xb_;
  u16* T = (z < zsplit) ? Ta : Tb;
  const int bz = (z < zsplit) ? z : z - zsplit;
  const int n0 = blockIdx.x * 64, c0 = blockIdx.y * 64;
  const float* Xb = X + (size_t)bz * CDIM * HW;
  u16* Tbp = T + (size_t)bz * HW * CDIM;
  const int tx = threadIdx.x, ty = threadIdx.y; // (64,4)
#pragma unroll
  for (int i = 0; i < 16; ++i)
    tile[ty + 4 * i][tx] = Xb[(size_t)(c0 + ty + 4 * i) * HW + n0 + tx];
  __syncthreads();
#pragma unroll
  for (int i = 0; i < 16; ++i)
    Tbp[(size_t)(n0 + ty + 4 * i) * CDIM + c0 + tx] = (u16)bfr(tile[tx][ty + 4 * i]);
}

// ---------------- merged Q/K projection GEMM (direct-global frags, R7-proven) ----------------
// z<8: Q = (queryT . WqT + bq) * 0.125 ; z>=8: K = keyT . WkT + bk.  D [HW,64].
__global__ __launch_bounds__(256) void gemm_qk(
    const u16* __restrict__ QT, const u16* __restrict__ KT,
    const u16* __restrict__ Wq, const u16* __restrict__ Wk,
    const float* __restrict__ bq, const float* __restrict__ bk,
    u16* __restrict__ Qo, u16* __restrict__ Ko)
{
  const int z = blockIdx.z;
  const bool isq = z < 8;
  const int bz = isq ? z : z - 8;
  const u16* A  = (isq ? QT : KT) + (size_t)bz * HW * CDIM;
  const u16* Bm = isq ? Wq : Wk;
  u16* D        = (isq ? Qo : Ko) + (size_t)bz * HW * CI_;
  const float* bias = isq ? bq : bk;
  const float alpha = isq ? 0.125f : 1.0f;

  const int tid = threadIdx.x, wid = tid >> 6, lane = tid & 63;
  const int lr = lane & 15, lg = lane >> 4;
  const int i0 = blockIdx.x * 128 + wid * 32;
  f32x4 acc[2][4];
#pragma unroll
  for (int rt = 0; rt < 2; ++rt)
#pragma unroll
    for (int ct = 0; ct < 4; ++ct) acc[rt][ct] = (f32x4){0.f, 0.f, 0.f, 0.f};

#pragma unroll 4
  for (int k0 = 0; k0 < CDIM; k0 += 32) {
    bf16x8 af[2], bf[4];
#pragma unroll
    for (int rt = 0; rt < 2; ++rt)
      af[rt] = *(const bf16x8*)(A + (size_t)(i0 + rt * 16 + lr) * CDIM + k0 + lg * 8);
#pragma unroll
    for (int ct = 0; ct < 4; ++ct)
      bf[ct] = *(const bf16x8*)(Bm + (size_t)(ct * 16 + lr) * CDIM + k0 + lg * 8);
#pragma unroll
    for (int rt = 0; rt < 2; ++rt)
#pragma unroll
      for (int ct = 0; ct < 4; ++ct)
        acc[rt][ct] = __builtin_amdgcn_mfma_f32_16x16x32_bf16(af[rt], bf[ct], acc[rt][ct], 0, 0, 0);
  }

#pragma unroll
  for (int rt = 0; rt < 2; ++rt)
#pragma unroll
    for (int ct = 0; ct < 4; ++ct)
#pragma unroll
      for (int r = 0; r < 4; ++r) {
        int i = i0 + rt * 16 + lg * 4 + r;
        int j = ct * 16 + lr;
        D[(size_t)i * CI_ + j] = (u16)bfr((acc[rt][ct][r] + bias[j]) * alpha);
      }
}

// ---------------- NT GEMM (direct-global frags, R7 version): V projection ----------------
__global__ __launch_bounds__(256) void gemm_nt(
    const u16* __restrict__ A, const u16* __restrict__ Bm, u16* __restrict__ D,
    const float* __restrict__ bias, int biasRow, float alpha,
    int lda, int ldb, int ldd, long aBatch, long bBatch, long dBatch, int Kd)
{
  const int tid = threadIdx.x, wid = tid >> 6, lane = tid & 63;
  const int lr = lane & 15, lg = lane >> 4;
  const int i0 = blockIdx.x * 128 + wid * 32;
  const int j0 = blockIdx.y * 64;
  const u16* Ab = A + blockIdx.z * aBatch;
  const u16* Bb = Bm + blockIdx.z * bBatch;
  f32x4 acc[2][4];
#pragma unroll
  for (int rt = 0; rt < 2; ++rt)
#pragma unroll
    for (int ct = 0; ct < 4; ++ct) acc[rt][ct] = (f32x4){0.f, 0.f, 0.f, 0.f};

#pragma unroll 4
  for (int k0 = 0; k0 < Kd; k0 += 32) {
    bf16x8 af[2], bf[4];
#pragma unroll
    for (int rt = 0; rt < 2; ++rt)
      af[rt] = *(const bf16x8*)(Ab + (size_t)(i0 + rt * 16 + lr) * lda + k0 + lg * 8);
#pragma unroll
    for (int ct = 0; ct < 4; ++ct)
      bf[ct] = *(const bf16x8*)(Bb + (size_t)(j0 + ct * 16 + lr) * ldb + k0 + lg * 8);
#pragma unroll
    for (int rt = 0; rt < 2; ++rt)
#pragma unroll
      for (int ct = 0; ct < 4; ++ct)
        acc[rt][ct] = __builtin_amdgcn_mfma_f32_16x16x32_bf16(af[rt], bf[ct], acc[rt][ct], 0, 0, 0);
  }

  u16* Db = D + blockIdx.z * dBatch;
#pragma unroll
  for (int rt = 0; rt < 2; ++rt)
#pragma unroll
    for (int ct = 0; ct < 4; ++ct)
#pragma unroll
      for (int r = 0; r < 4; ++r) {
        int i = i0 + rt * 16 + lg * 4 + r;
        int j = j0 + ct * 16 + lr;
        float v = (acc[rt][ct][r] + (biasRow ? bias[i] : bias[j])) * alpha;
        Db[(size_t)i * ldd + j] = (u16)bfr(v);
      }
}

// ---------------- fused flash attention + gamma*attn + value ----------------
// R7 kernel, byte-identical (measured 240us twice, MfmaUtil 38%, no spill).
__global__ __launch_bounds__(256, 2) void flash_attn(
    const u16* __restrict__ Q, const u16* __restrict__ K, const u16* __restrict__ V,
    const float* __restrict__ value, const float* __restrict__ gammap, float* __restrict__ out)
{
  __shared__ u16 Ks[2][64 * KROW];    // 2 x 9.2 KB  [m=64][ci=64 +pad]
  __shared__ u16 Vs[2][128 * VROW];   // 2 x 18.4 KB [c=128][m=64 +pad]

  const int b  = blockIdx.x & 7;
  const int rb = (blockIdx.x >> 3) & 15;
  const int ch = blockIdx.x >> 7;
  const int tid = threadIdx.x, wid = tid >> 6, lane = tid & 63;
  const int l31 = lane & 31, h = lane >> 5;

  const int n0 = rb * 256 + wid * 64;   // wave q-row base
  const int c0 = ch * 128;              // block c base

  const u16* Qb = Q + (size_t)b * HW * CI_;
  const u16* Kb = K + (size_t)b * HW * CI_;
  const u16* Vb = V + (size_t)b * CDIM * HW + (size_t)c0 * HW;

  // Q B-frags: col n = n0 + ng*32 + l31, k = kk*16 + h*8 + j
  bf16x8 qf[2][4];
#pragma unroll
  for (int ng = 0; ng < 2; ++ng)
#pragma unroll
    for (int kk = 0; kk < 4; ++kk)
      qf[ng][kk] = *(const bf16x8*)(Qb + (size_t)(n0 + ng * 32 + l31) * CI_ + kk * 16 + h * 8);

  f32x16 acc[2][4];
#pragma unroll
  for (int ng = 0; ng < 2; ++ng)
#pragma unroll
    for (int ct = 0; ct < 4; ++ct)
#pragma unroll
      for (int i = 0; i < 16; ++i) acc[ng][ct][i] = 0.f;
  float lp0 = 0.f, lp1 = 0.f;

  // staging maps: K tile 8KB (4 thr/row x 2 b128), V tile 16KB (2 thr/row x 4 b128)
  const int krow_ = tid >> 2, kcol = (tid & 3) * 8;
  const int vrow_ = tid >> 1, vcol = (tid & 1) * 32;
  uint4 kr[2], vr[4];

#define SISSUE(T) do { \
    const u16* kp_ = Kb + (size_t)((T) * MT + krow_) * CI_ + kcol; \
    kr[0] = *(const uint4*)kp_; \
    kr[1] = *(const uint4*)(kp_ + 32); \
    const u16* vp_ = Vb + (size_t)vrow_ * HW + (T) * MT + vcol; \
    _Pragma("unroll") \
    for (int j = 0; j < 4; ++j) vr[j] = *(const uint4*)(vp_ + j * 8); \
  } while (0)

#define SWRITE(BUF) do { \
    *(uint4*)(&Ks[BUF][krow_ * KROW + kcol]) = kr[0]; \
    *(uint4*)(&Ks[BUF][krow_ * KROW + kcol + 32]) = kr[1]; \
    _Pragma("unroll") \
    for (int j = 0; j < 4; ++j) \
      *(uint4*)(&Vs[BUF][vrow_ * VROW + vcol + j * 8]) = vr[j]; \
  } while (0)

  SISSUE(0); SWRITE(0);
  __syncthreads();

  for (int t = 0; t < NTIL; ++t) {
    const int par = t & 1;
    if (t + 1 < NTIL) SISSUE(t + 1);   // next-tile global loads; land during compute

#pragma unroll
    for (int s = 0; s < 2; ++s) {      // m-strip of 32 within the 64-m tile
      // K A-frags: row m = s*32 + l31, k = kk*16 + h*8 + j
      bf16x8 kf[4];
#pragma unroll
      for (int kk = 0; kk < 4; ++kk)
        kf[kk] = *(const bf16x8*)(&Ks[par][(s * 32 + l31) * KROW + kk * 16 + h * 8]);

      bf16x8 pa[2][2];                 // [ng][kk-local] PV B-frags for this strip
#pragma unroll
      for (int ng = 0; ng < 2; ++ng) {
        f32x16 st;
#pragma unroll
        for (int i = 0; i < 16; ++i) st[i] = 0.f;
#pragma unroll
        for (int kk = 0; kk < 4; ++kk)
          st = __builtin_amdgcn_mfma_f32_32x32x16_bf16(kf[kk], qf[ng][kk], st, 0, 0, 0);

        // exp + row-sum partial (lane holds 16 of 32 m-values for row n=l31)
        float p[16]; float rs = 0.f;
#pragma unroll
        for (int r = 0; r < 16; ++r) { p[r] = __expf(st[r]); rs += p[r]; }
        if (ng == 0) lp0 += rs; else lp1 += rs;

        // T12 pack: quads m(r) = (r&3) + 8*(r>>2) + 4h (within strip)
        u32 qa0 = cvtpk(p[0],  p[1]),  qa1 = cvtpk(p[2],  p[3]);   // m 4h+0..3
        u32 qb0 = cvtpk(p[4],  p[5]),  qb1 = cvtpk(p[6],  p[7]);   // m 8+4h+0..3
        u32 qc0 = cvtpk(p[8],  p[9]),  qc1 = cvtpk(p[10], p[11]);  // m 16+4h+0..3
        u32 qd0 = cvtpk(p[12], p[13]), qd1 = cvtpk(p[14], p[15]);  // m 24+4h+0..3
        // in-place half swap: h=0 ends {own qa, partner qa} = m0..7; h=1 {partner qb, own qb} = m8..15
        asm("v_permlane32_swap_b32 %0, %1" : "+v"(qa0), "+v"(qb0));
        asm("v_permlane32_swap_b32 %0, %1" : "+v"(qa1), "+v"(qb1));
        asm("v_permlane32_swap_b32 %0, %1" : "+v"(qc0), "+v"(qd0));
        asm("v_permlane32_swap_b32 %0, %1" : "+v"(qc1), "+v"(qd1));
        fragu f0; f0.w[0] = qa0; f0.w[1] = qa1; f0.w[2] = qb0; f0.w[3] = qb1;
        pa[ng][0] = f0.v;
        fragu f1; f1.w[0] = qc0; f1.w[1] = qc1; f1.w[2] = qd0; f1.w[3] = qd1;
        pa[ng][1] = f1.v;
      }

      // PV partial for this strip: kk = 2s + kkl
      __builtin_amdgcn_s_setprio(1);
#pragma unroll
      for (int ct = 0; ct < 4; ++ct)
#pragma unroll
        for (int kkl = 0; kkl < 2; ++kkl) {
          bf16x8 vf = *(const bf16x8*)(&Vs[par][(ct * 32 + l31) * VROW + (2 * s + kkl) * 16 + h * 8]);
          acc[0][ct] = __builtin_amdgcn_mfma_f32_32x32x16_bf16(vf, pa[0][kkl], acc[0][ct], 0, 0, 0);
          acc[1][ct] = __builtin_amdgcn_mfma_f32_32x32x16_bf16(vf, pa[1][kkl], acc[1][ct], 0, 0, 0);
        }
      __builtin_amdgcn_s_setprio(0);
    }

    if (t + 1 < NTIL) SWRITE((t + 1) & 1);
    __syncthreads();   // single barrier: protects dbuf parity both directions
  }

  // ---- epilogue: per-wave LDS transpose so value/out stay coalesced ----
  __syncthreads();   // everyone done with Ks/Vs; reuse as scratch
  float* Tls = (float*)((char*)&Vs[0][0] + wid * 4352);  // 32c x 33n f32 = 4224B per wave
  const float g = gammap[0];
  const float ls0 = lp0 + __shfl_xor(lp0, 32);
  const float ls1 = lp1 + __shfl_xor(lp1, 32);
  const float ri0 = g / ls0, ri1 = g / ls1;   // gamma folded; lane's n = l31 (per ng)
  const size_t obase = (size_t)b * CDIM * HW;
#pragma unroll
  for (int ng = 0; ng < 2; ++ng) {
    const float ri = ng ? ri1 : ri0;
#pragma unroll
    for (int ct = 0; ct < 4; ++ct) {
      // write: Tls[c_local][n_local]
#pragma unroll
      for (int r = 0; r < 16; ++r) {
        int cc = (r & 3) + 8 * (r >> 2) + 4 * h;
        Tls[cc * 33 + l31] = acc[ng][ct][r] * ri;
      }
      // read coalesced: lane -> c = l31, n = 2p + h
#pragma unroll
      for (int p = 0; p < 16; ++p) {
        float v = Tls[l31 * 33 + 2 * p + h];
        int n = n0 + ng * 32 + 2 * p + h;
        int c = c0 + ct * 32 + l31;
        size_t idx = obase + (size_t)n * CDIM + c;
        out[idx] = v + value[idx];
      }
    }
  }
}

extern "C" void kernel_launch(void* const* d_in, const int* in_sizes, int n_in,
                              void* d_out, int out_size, void* d_ws, size_t ws_size,
                              hipStream_t stream) {
  const float* query = (const float*)d_in[0];
  const float* key   = (const float*)d_in[1];
  const float* value = (const float*)d_in[2];
  const float* Wq    = (const float*)d_in[3];
  const float* bq    = (const float*)d_in[4];
  const float* Wk    = (const float*)d_in[5];
  const float* bk    = (const float*)d_in[6];
  const float* Wv    = (const float*)d_in[7];
  const float* bv    = (const float*)d_in[8];
  const float* gamma = (const float*)d_in[9];

  char* ws = (char*)d_ws;
  u16* XT  = (u16*)(ws);               // 33,554,432 B  [B,HW,C] bf16 (query-T, then value-T)
  u16* Qb  = (u16*)(ws + 33554432);    //  4,194,304 B  [B,HW,CI]
  u16* Kb  = (u16*)(ws + 37748736);    //  4,194,304 B  [B,HW,CI]
  u16* Vb  = (u16*)(ws + 41943040);    // 33,554,432 B  key-T (temp), then [B,C,HW] V
  u16* WQb = (u16*)(ws + 75497472);    //     65,536 B
  u16* WKb = (u16*)(ws + 75563008);    //     65,536 B
  u16* WVb = (u16*)(ws + 75628544);    //    524,288 B

  // 1) all three weight casts in one launch
  cast3<<<(CDIM * CDIM) / 256, 256, 0, stream>>>(Wq, Wk, Wv, WQb, WKb, WVb);

  // 2) transpose query -> XT and key -> Vb(temp) in one launch
  transpose_cast2<<<dim3(HW / 64, CDIM / 64, 16), dim3(64, 4), 0, stream>>>(
      query, key, XT, Vb, 8);

  // 3) Q and K projections in one launch (z<8: Q from XT; z>=8: K from Vb-temp)
  gemm_qk<<<dim3(HW / 128, 1, 16), 256, 0, stream>>>(
      XT, Vb, WQb, WKb, bq, bk, Qb, Kb);

  // 4) transpose value -> XT (query-T no longer needed)
  transpose_cast2<<<dim3(HW / 64, CDIM / 64, 8), dim3(64, 4), 0, stream>>>(
      value, value, XT, XT, 8);

  // 5) V^T = Wv (value^T)^T + bv  stored [B, C, HW]  (overwrites key-T temp)
  gemm_nt<<<dim3(CDIM / 128, HW / 64, B_), 256, 0, stream>>>(
      WVb, XT, Vb, bv, 1, 1.0f, CDIM, CDIM, HW,
      0L, (long)HW * CDIM, (long)CDIM * HW, CDIM);

  // 6) fused flash attention + epilogue
  flash_attn<<<512, 256, 0, stream>>>(Qb, Kb, Vb, value, gamma, (float*)d_out);
}

// Round 10
// 397.645 us; speedup vs baseline: 1.0785x; 1.0002x over previous
//
#include <hip/hip_runtime.h>
#include <hip/hip_bf16.h>
#include <math.h>

// Problem constants
#define B_    8
#define CDIM  512
#define HW    4096
#define CI_   64
#define MT    64            // kv rows per tile
#define NTIL  (HW/MT)       // 64 tiles

typedef __attribute__((ext_vector_type(8))) short bf16x8;
typedef __attribute__((ext_vector_type(4))) float f32x4;
typedef __attribute__((ext_vector_type(16))) float f32x16;
typedef unsigned short u16;
typedef unsigned int   u32;

union fragu { bf16x8 v; u32 w[4]; };

// fp32 -> bf16 bits with RNE rounding
__device__ __forceinline__ u32 bfr(float f) {
  u32 x = __float_as_uint(f);
  return (x + 0x7fffu + ((x >> 16) & 1u)) >> 16;
}
// packed 2xf32 -> bf16x2 (RNE) via HW instruction
__device__ __forceinline__ u32 cvtpk(float a, float b) {
  u32 r;
  asm("v_cvt_pk_bf16_f32 %0, %1, %2" : "=v"(r) : "v"(a), "v"(b));
  return r;
}
// raw v_exp_f32 = exp2 (log2e is pre-folded into Q's projection scale)
__device__ __forceinline__ float hexp2(float x) {
  float r;
  asm("v_exp_f32 %0, %1" : "=v"(r) : "v"(x));
  return r;
}

// global -> LDS direct DMA, 16B/lane (dest = wave-uniform base + lane*16, linear)
typedef const __attribute__((address_space(1))) void g1cv;
typedef __attribute__((address_space(3))) void l3v;
#define GLDS16(g, l) __builtin_amdgcn_global_load_lds((g1cv*)(g), (l3v*)(l), 16, 0, 0)

// ---------------- fused cast fp32 -> bf16 for the three weight tensors ----------------
__global__ void cast3(const float* __restrict__ wq, const float* __restrict__ wk,
                      const float* __restrict__ wv, u16* __restrict__ oq,
                      u16* __restrict__ ok, u16* __restrict__ ov) {
  int i = blockIdx.x * 256 + threadIdx.x;
  if (i < CI_ * CDIM) { oq[i] = (u16)bfr(wq[i]); ok[i] = (u16)bfr(wk[i]); }
  ov[i] = (u16)bfr(wv[i]);   // grid sized to CDIM*CDIM
}

// ---------------- transpose+cast x2: X [C,HW] f32 -> T [HW,C] bf16 ----------------
// 64x64 tiles, block (64,4). z < zsplit -> (Xa,Ta) else (Xb,Tb). Full-width 128B stores.
__global__ void transpose_cast2(const float* __restrict__ Xa, const float* __restrict__ Xb_,
                                u16* __restrict__ Ta, u16* __restrict__ Tb, int zsplit) {
  __shared__ float tile[64][65];
  const int z = blockIdx.z;
  const float* X = (z < zsplit) ? Xa : Xb_;
  u16* T = (z < zsplit) ? Ta : Tb;
  const int bz = (z < zsplit) ? z : z - zsplit;
  const int n0 = blockIdx.x * 64, c0 = blockIdx.y * 64;
  const float* Xb = X + (size_t)bz * CDIM * HW;
  u16* Tbp = T + (size_t)bz * HW * CDIM;
  const int tx = threadIdx.x, ty = threadIdx.y; // (64,4)
#pragma unroll
  for (int i = 0; i < 16; ++i)
    tile[ty + 4 * i][tx] = Xb[(size_t)(c0 + ty + 4 * i) * HW + n0 + tx];
  __syncthreads();
#pragma unroll
  for (int i = 0; i < 16; ++i)
    Tbp[(size_t)(n0 + ty + 4 * i) * CDIM + c0 + tx] = (u16)bfr(tile[tx][ty + 4 * i]);
}

// ---------------- merged Q/K projection GEMM (direct-global frags, R7-proven) ----------------
// z<8: Q = (queryT . WqT + bq) * (0.125*log2e) ; z>=8: K = keyT . WkT + bk.  D [HW,64].
// log2(e) folded into Q so flash's softmax uses raw v_exp_f32 (exp2).
__global__ __launch_bounds__(256) void gemm_qk(
    const u16* __restrict__ QT, const u16* __restrict__ KT,
    const u16* __restrict__ Wq, const u16* __restrict__ Wk,
    const float* __restrict__ bq, const float* __restrict__ bk,
    u16* __restrict__ Qo, u16* __restrict__ Ko)
{
  const int z = blockIdx.z;
  const bool isq = z < 8;
  const int bz = isq ? z : z - 8;
  const u16* A  = (isq ? QT : KT) + (size_t)bz * HW * CDIM;
  const u16* Bm = isq ? Wq : Wk;
  u16* D        = (isq ? Qo : Ko) + (size_t)bz * HW * CI_;
  const float* bias = isq ? bq : bk;
  const float alpha = isq ? 0.125f * 1.44269504f : 1.0f;

  const int tid = threadIdx.x, wid = tid >> 6, lane = tid & 63;
  const int lr = lane & 15, lg = lane >> 4;
  const int i0 = blockIdx.x * 128 + wid * 32;
  f32x4 acc[2][4];
#pragma unroll
  for (int rt = 0; rt < 2; ++rt)
#pragma unroll
    for (int ct = 0; ct < 4; ++ct) acc[rt][ct] = (f32x4){0.f, 0.f, 0.f, 0.f};

#pragma unroll 4
  for (int k0 = 0; k0 < CDIM; k0 += 32) {
    bf16x8 af[2], bf[4];
#pragma unroll
    for (int rt = 0; rt < 2; ++rt)
      af[rt] = *(const bf16x8*)(A + (size_t)(i0 + rt * 16 + lr) * CDIM + k0 + lg * 8);
#pragma unroll
    for (int ct = 0; ct < 4; ++ct)
      bf[ct] = *(const bf16x8*)(Bm + (size_t)(ct * 16 + lr) * CDIM + k0 + lg * 8);
#pragma unroll
    for (int rt = 0; rt < 2; ++rt)
#pragma unroll
      for (int ct = 0; ct < 4; ++ct)
        acc[rt][ct] = __builtin_amdgcn_mfma_f32_16x16x32_bf16(af[rt], bf[ct], acc[rt][ct], 0, 0, 0);
  }

#pragma unroll
  for (int rt = 0; rt < 2; ++rt)
#pragma unroll
    for (int ct = 0; ct < 4; ++ct)
#pragma unroll
      for (int r = 0; r < 4; ++r) {
        int i = i0 + rt * 16 + lg * 4 + r;
        int j = ct * 16 + lr;
        D[(size_t)i * CI_ + j] = (u16)bfr((acc[rt][ct][r] + bias[j]) * alpha);
      }
}

// ---------------- NT GEMM (direct-global frags, R7 version): V projection ----------------
__global__ __launch_bounds__(256) void gemm_nt(
    const u16* __restrict__ A, const u16* __restrict__ Bm, u16* __restrict__ D,
    const float* __restrict__ bias, int biasRow, float alpha,
    int lda, int ldb, int ldd, long aBatch, long bBatch, long dBatch, int Kd)
{
  const int tid = threadIdx.x, wid = tid >> 6, lane = tid & 63;
  const int lr = lane & 15, lg = lane >> 4;
  const int i0 = blockIdx.x * 128 + wid * 32;
  const int j0 = blockIdx.y * 64;
  const u16* Ab = A + blockIdx.z * aBatch;
  const u16* Bb = Bm + blockIdx.z * bBatch;
  f32x4 acc[2][4];
#pragma unroll
  for (int rt = 0; rt < 2; ++rt)
#pragma unroll
    for (int ct = 0; ct < 4; ++ct) acc[rt][ct] = (f32x4){0.f, 0.f, 0.f, 0.f};

#pragma unroll 4
  for (int k0 = 0; k0 < Kd; k0 += 32) {
    bf16x8 af[2], bf[4];
#pragma unroll
    for (int rt = 0; rt < 2; ++rt)
      af[rt] = *(const bf16x8*)(Ab + (size_t)(i0 + rt * 16 + lr) * lda + k0 + lg * 8);
#pragma unroll
    for (int ct = 0; ct < 4; ++ct)
      bf[ct] = *(const bf16x8*)(Bb + (size_t)(j0 + ct * 16 + lr) * ldb + k0 + lg * 8);
#pragma unroll
    for (int rt = 0; rt < 2; ++rt)
#pragma unroll
      for (int ct = 0; ct < 4; ++ct)
        acc[rt][ct] = __builtin_amdgcn_mfma_f32_16x16x32_bf16(af[rt], bf[ct], acc[rt][ct], 0, 0, 0);
  }

  u16* Db = D + blockIdx.z * dBatch;
#pragma unroll
  for (int rt = 0; rt < 2; ++rt)
#pragma unroll
    for (int ct = 0; ct < 4; ++ct)
#pragma unroll
      for (int r = 0; r < 4; ++r) {
        int i = i0 + rt * 16 + lg * 4 + r;
        int j = j0 + ct * 16 + lr;
        float v = (acc[rt][ct][r] + (biasRow ? bias[i] : bias[j])) * alpha;
        Db[(size_t)i * ldd + j] = (u16)bfr(v);
      }
}

// ---------------- fused flash attention + gamma*attn + value ----------------
// R7 structure, staging switched to global_load_lds with pre-swizzled sources:
// LDS rows linear 64 u16 (128B); chunk involution j ^= (row&7) applied to the
// global SOURCE address (write side) and to the ds_read offset (read side).
// P = exp2(S) (log2e folded into Q), l = sum P. No max-tracking (|S| small).
__global__ __launch_bounds__(256, 2) void flash_attn(
    const u16* __restrict__ Q, const u16* __restrict__ K, const u16* __restrict__ V,
    const float* __restrict__ value, const float* __restrict__ gammap, float* __restrict__ out)
{
  __shared__ u16 Ks[2][64 * 64];     // 2 x 8 KB   [m=64][ci=64], swizzled chunks
  __shared__ u16 Vs[2][128 * 64];    // 2 x 16 KB  [c=128][m=64], swizzled chunks

  const int b  = blockIdx.x & 7;
  const int rb = (blockIdx.x >> 3) & 15;
  const int ch = blockIdx.x >> 7;
  const int tid = threadIdx.x, wid = tid >> 6, lane = tid & 63;
  const int l31 = lane & 31, h = lane >> 5;

  const int n0 = rb * 256 + wid * 64;   // wave q-row base
  const int c0 = ch * 128;              // block c base

  const u16* Qb = Q + (size_t)b * HW * CI_;
  const u16* Kb = K + (size_t)b * HW * CI_;
  const u16* Vb = V + (size_t)b * CDIM * HW + (size_t)c0 * HW;

  // Q B-frags: col n = n0 + ng*32 + l31, k = kk*16 + h*8 + j
  bf16x8 qf[2][4];
#pragma unroll
  for (int ng = 0; ng < 2; ++ng)
#pragma unroll
    for (int kk = 0; kk < 4; ++kk)
      qf[ng][kk] = *(const bf16x8*)(Qb + (size_t)(n0 + ng * 32 + l31) * CI_ + kk * 16 + h * 8);

  f32x16 acc[2][4];
#pragma unroll
  for (int ng = 0; ng < 2; ++ng)
#pragma unroll
    for (int ct = 0; ct < 4; ++ct)
#pragma unroll
      for (int i = 0; i < 16; ++i) acc[ng][ct][i] = 0.f;
  float lp0 = 0.f, lp1 = 0.f;

  // ---- staging sources (pre-swizzled): lane -> (row = 8-block + lane>>3, chunk = lane&7)
  // LDS slot (row, chunk) receives global chunk (chunk ^ (row&7)); row&7 == lane>>3 & 7.
  const int lrow = lane >> 3, lchk = lane & 7;
  const int swz = lchk ^ lrow;
  // K: wave wid stages rows [wid*16, wid*16+16) (2 instrs x 8 rows)
  const u16* kcur = Kb + (size_t)(wid * 16 + lrow) * CI_ + swz * 8;
  // V: wave wid stages rows [wid*32, wid*32+32) (4 instrs x 8 rows)
  const u16* vcur = Vb + (size_t)(wid * 32 + lrow) * HW + swz * 8;
  const int kofs = wid * 16 * 64, vofs = wid * 32 * 64;   // u16 LDS offsets

#define ISSUE(BUF) do { \
    GLDS16(kcur,              &Ks[BUF][kofs]); \
    GLDS16(kcur + 8 * CI_,    &Ks[BUF][kofs + 8 * 64]); \
    GLDS16(vcur,              &Vs[BUF][vofs]); \
    GLDS16(vcur + 8 * HW,     &Vs[BUF][vofs + 8 * 64]); \
    GLDS16(vcur + 16 * HW,    &Vs[BUF][vofs + 16 * 64]); \
    GLDS16(vcur + 24 * HW,    &Vs[BUF][vofs + 24 * 64]); \
  } while (0)

  ISSUE(0);
  __syncthreads();   // compiler-inserted vmcnt(0) drains the DMA

  for (int t = 0; t < NTIL; ++t) {
    const int par = t & 1;
    if (t + 1 < NTIL) {            // issue next-tile DMA; drains at this tile's end barrier
      kcur += MT * CI_;
      vcur += MT;
      ISSUE(par ^ 1);
    }

#pragma unroll
    for (int s = 0; s < 2; ++s) {  // m-strip of 32 within the 64-m tile
      // K A-frags: row m = s*32 + l31, chunk j = 2kk+h, swizzled by (m&7)==(l31&7)
      bf16x8 kf[4];
#pragma unroll
      for (int kk = 0; kk < 4; ++kk)
        kf[kk] = *(const bf16x8*)(&Ks[par][(s * 32 + l31) * 64 + (((2 * kk + h) ^ (l31 & 7)) << 3)]);

      bf16x8 pa[2][2];             // [ng][kk-local] PV B-frags for this strip
#pragma unroll
      for (int ng = 0; ng < 2; ++ng) {
        f32x16 st;
#pragma unroll
        for (int i = 0; i < 16; ++i) st[i] = 0.f;
#pragma unroll
        for (int kk = 0; kk < 4; ++kk)
          st = __builtin_amdgcn_mfma_f32_32x32x16_bf16(kf[kk], qf[ng][kk], st, 0, 0, 0);

        // P = exp2(S) (log2e pre-folded); row-sum partial
        float p[16]; float rs = 0.f;
#pragma unroll
        for (int r = 0; r < 16; ++r) { p[r] = hexp2(st[r]); rs += p[r]; }
        if (ng == 0) lp0 += rs; else lp1 += rs;

        // T12 pack: quads m(r) = (r&3) + 8*(r>>2) + 4h (within strip)
        u32 qa0 = cvtpk(p[0],  p[1]),  qa1 = cvtpk(p[2],  p[3]);   // m 4h+0..3
        u32 qb0 = cvtpk(p[4],  p[5]),  qb1 = cvtpk(p[6],  p[7]);   // m 8+4h+0..3
        u32 qc0 = cvtpk(p[8],  p[9]),  qc1 = cvtpk(p[10], p[11]);  // m 16+4h+0..3
        u32 qd0 = cvtpk(p[12], p[13]), qd1 = cvtpk(p[14], p[15]);  // m 24+4h+0..3
        // in-place half swap: h=0 ends {own qa, partner qa} = m0..7; h=1 {partner qb, own qb} = m8..15
        asm("v_permlane32_swap_b32 %0, %1" : "+v"(qa0), "+v"(qb0));
        asm("v_permlane32_swap_b32 %0, %1" : "+v"(qa1), "+v"(qb1));
        asm("v_permlane32_swap_b32 %0, %1" : "+v"(qc0), "+v"(qd0));
        asm("v_permlane32_swap_b32 %0, %1" : "+v"(qc1), "+v"(qd1));
        fragu f0; f0.w[0] = qa0; f0.w[1] = qa1; f0.w[2] = qb0; f0.w[3] = qb1;
        pa[ng][0] = f0.v;
        fragu f1; f1.w[0] = qc0; f1.w[1] = qc1; f1.w[2] = qd0; f1.w[3] = qd1;
        pa[ng][1] = f1.v;
      }

      // PV partial for this strip: V chunk j = 4s + 2kkl + h, swizzled by (c&7)==(l31&7)
      __builtin_amdgcn_s_setprio(1);
#pragma unroll
      for (int ct = 0; ct < 4; ++ct)
#pragma unroll
        for (int kkl = 0; kkl < 2; ++kkl) {
          bf16x8 vf = *(const bf16x8*)(&Vs[par][(ct * 32 + l31) * 64 + (((4 * s + 2 * kkl + h) ^ (l31 & 7)) << 3)]);
          acc[0][ct] = __builtin_amdgcn_mfma_f32_32x32x16_bf16(vf, pa[0][kkl], acc[0][ct], 0, 0, 0);
          acc[1][ct] = __builtin_amdgcn_mfma_f32_32x32x16_bf16(vf, pa[1][kkl], acc[1][ct], 0, 0, 0);
        }
      __builtin_amdgcn_s_setprio(0);
    }

    __syncthreads();   // single barrier: drains next-tile DMA (vmcnt0) + fences dbuf parity
  }

  // ---- epilogue: per-wave LDS transpose so value/out stay coalesced ----
  __syncthreads();   // everyone done with Ks/Vs; reuse as scratch
  float* Tls = (float*)((char*)&Vs[0][0] + wid * 4352);  // 32c x 33n f32 = 4224B per wave
  const float g = gammap[0];
  const float ls0 = lp0 + __shfl_xor(lp0, 32);
  const float ls1 = lp1 + __shfl_xor(lp1, 32);
  const float ri0 = g / ls0, ri1 = g / ls1;   // gamma folded; lane's n = l31 (per ng)
  const size_t obase = (size_t)b * CDIM * HW;
#pragma unroll
  for (int ng = 0; ng < 2; ++ng) {
    const float ri = ng ? ri1 : ri0;
#pragma unroll
    for (int ct = 0; ct < 4; ++ct) {
      // write: Tls[c_local][n_local]
#pragma unroll
      for (int r = 0; r < 16; ++r) {
        int cc = (r & 3) + 8 * (r >> 2) + 4 * h;
        Tls[cc * 33 + l31] = acc[ng][ct][r] * ri;
      }
      // read coalesced: lane -> c = l31, n = 2p + h
#pragma unroll
      for (int p = 0; p < 16; ++p) {
        float v = Tls[l31 * 33 + 2 * p + h];
        int n = n0 + ng * 32 + 2 * p + h;
        int c = c0 + ct * 32 + l31;
        size_t idx = obase + (size_t)n * CDIM + c;
        out[idx] = v + value[idx];
      }
    }
  }
}

extern "C" void kernel_launch(void* const* d_in, const int* in_sizes, int n_in,
                              void* d_out, int out_size, void* d_ws, size_t ws_size,
                              hipStream_t stream) {
  const float* query = (const float*)d_in[0];
  const float* key   = (const float*)d_in[1];
  const float* value = (const float*)d_in[2];
  const float* Wq    = (const float*)d_in[3];
  const float* bq    = (const float*)d_in[4];
  const float* Wk    = (const float*)d_in[5];
  const float* bk    = (const float*)d_in[6];
  const float* Wv    = (const float*)d_in[7];
  const float* bv    = (const float*)d_in[8];
  const float* gamma = (const float*)d_in[9];

  char* ws = (char*)d_ws;
  u16* XT  = (u16*)(ws);               // 33,554,432 B  [B,HW,C] bf16 (query-T, then value-T)
  u16* Qb  = (u16*)(ws + 33554432);    //  4,194,304 B  [B,HW,CI]
  u16* Kb  = (u16*)(ws + 37748736);    //  4,194,304 B  [B,HW,CI]
  u16* Vb  = (u16*)(ws + 41943040);    // 33,554,432 B  key-T (temp), then [B,C,HW] V
  u16* WQb = (u16*)(ws + 75497472);    //     65,536 B
  u16* WKb = (u16*)(ws + 75563008);    //     65,536 B
  u16* WVb = (u16*)(ws + 75628544);    //    524,288 B

  // 1) all three weight casts in one launch
  cast3<<<(CDIM * CDIM) / 256, 256, 0, stream>>>(Wq, Wk, Wv, WQb, WKb, WVb);

  // 2) transpose query -> XT and key -> Vb(temp) in one launch
  transpose_cast2<<<dim3(HW / 64, CDIM / 64, 16), dim3(64, 4), 0, stream>>>(
      query, key, XT, Vb, 8);

  // 3) Q and K projections in one launch (z<8: Q from XT; z>=8: K from Vb-temp)
  gemm_qk<<<dim3(HW / 128, 1, 16), 256, 0, stream>>>(
      XT, Vb, WQb, WKb, bq, bk, Qb, Kb);

  // 4) transpose value -> XT (query-T no longer needed)
  transpose_cast2<<<dim3(HW / 64, CDIM / 64, 8), dim3(64, 4), 0, stream>>>(
      value, value, XT, XT, 8);

  // 5) V^T = Wv (value^T)^T + bv  stored [B, C, HW]  (overwrites key-T temp)
  gemm_nt<<<dim3(CDIM / 128, HW / 64, B_), 256, 0, stream>>>(
      WVb, XT, Vb, bv, 1, 1.0f, CDIM, CDIM, HW,
      0L, (long)HW * CDIM, (long)CDIM * HW, CDIM);

  // 6) fused flash attention + epilogue
  flash_attn<<<512, 256, 0, stream>>>(Qb, Kb, Vb, value, gamma, (float*)d_out);
}

// Round 11
// 311.715 us; speedup vs baseline: 1.3758x; 1.2757x over previous
//
#include <hip/hip_runtime.h>
#include <hip/hip_bf16.h>
#include <math.h>

// Problem constants
#define B_    8
#define CDIM  512
#define HW    4096
#define CI_   64
#define MT    64            // kv rows per tile
#define NTIL  (HW/MT)       // 64 tiles

typedef __attribute__((ext_vector_type(8))) short bf16x8;
typedef __attribute__((ext_vector_type(4))) float f32x4;
typedef __attribute__((ext_vector_type(16))) float f32x16;
typedef unsigned short u16;
typedef unsigned int   u32;

union fragu { bf16x8 v; u32 w[4]; };

// fp32 -> bf16 bits with RNE rounding
__device__ __forceinline__ u32 bfr(float f) {
  u32 x = __float_as_uint(f);
  return (x + 0x7fffu + ((x >> 16) & 1u)) >> 16;
}
// packed 2xf32 -> bf16x2 (RNE) via HW instruction
__device__ __forceinline__ u32 cvtpk(float a, float b) {
  u32 r;
  asm("v_cvt_pk_bf16_f32 %0, %1, %2" : "=v"(r) : "v"(a), "v"(b));
  return r;
}
// raw v_exp_f32 = exp2 (log2e is pre-folded into Q's projection scale)
__device__ __forceinline__ float hexp2(float x) {
  float r;
  asm("v_exp_f32 %0, %1" : "=v"(r) : "v"(x));
  return r;
}

// global -> LDS direct DMA, 16B/lane (dest = wave-uniform base + lane*16, linear)
typedef const __attribute__((address_space(1))) void g1cv;
typedef __attribute__((address_space(3))) void l3v;
#define GLDS16(g, l) __builtin_amdgcn_global_load_lds((g1cv*)(g), (l3v*)(l), 16, 0, 0)

#define MFMA16(a, b, c) __builtin_amdgcn_mfma_f32_16x16x32_bf16(a, b, c, 0, 0, 0)

// ---------------- fused cast fp32 -> bf16 for the three weight tensors ----------------
__global__ void cast3(const float* __restrict__ wq, const float* __restrict__ wk,
                      const float* __restrict__ wv, u16* __restrict__ oq,
                      u16* __restrict__ ok, u16* __restrict__ ov) {
  int i = blockIdx.x * 256 + threadIdx.x;
  if (i < CI_ * CDIM) { oq[i] = (u16)bfr(wq[i]); ok[i] = (u16)bfr(wk[i]); }
  ov[i] = (u16)bfr(wv[i]);   // grid sized to CDIM*CDIM
}

// ---------------- fused Q/K projection: transpose+cast folded into the GEMM ----------------
// D[n,o] = (sum_c X[c,n] * W[o,c] + bias[o]) * alpha, X f32 [C,HW], D bf16 [HW,64].
// z<8: Q from query (alpha = 0.125*log2e folded for flash's exp2); z>=8: K from key.
// Block 256 thr = 4 waves; block tile 128n x 64o; K-loop over C in steps of 64.
// X staged as f32 [64c][128n +1pad] (dbuf, coalesced 128B-group loads); A-frags
// read column-wise (8 x b32, 2-way bank = free) and packed to bf16 via cvt_pk.
__global__ __launch_bounds__(256) void proj_qk(
    const float* __restrict__ query, const float* __restrict__ key,
    const u16* __restrict__ Wq, const u16* __restrict__ Wk,
    const float* __restrict__ bq, const float* __restrict__ bk,
    u16* __restrict__ Qo, u16* __restrict__ Ko)
{
  __shared__ float Xs[2][64 * 129];   // 2 x 33 KB

  const int z = blockIdx.z;
  const bool isq = z < 8;
  const int bz = isq ? z : z - 8;
  const float* X = (isq ? query : key) + (size_t)bz * CDIM * HW;
  const u16* W = isq ? Wq : Wk;
  const float* bias = isq ? bq : bk;
  const float alpha = isq ? 0.125f * 1.44269504f : 1.0f;
  u16* D = (isq ? Qo : Ko) + (size_t)bz * HW * CI_;

  const int tid = threadIdx.x, wid = tid >> 6, lane = tid & 63;
  const int lr = lane & 15, lg = lane >> 4;
  const int n0 = blockIdx.x * 128;

  // staging map: 8 thr/row (128B groups), 32 rows/pass x 2 passes
  const int srow = tid >> 3;            // 0..31
  const int scol = (tid & 7) * 4;       // f32 col base; + 32*jj
  uint4 sx[2][4];

#define PQLOAD(T) do { \
    _Pragma("unroll") \
    for (int p = 0; p < 2; ++p) \
      _Pragma("unroll") \
      for (int jj = 0; jj < 4; ++jj) \
        sx[p][jj] = *(const uint4*)(X + (size_t)((T) * 64 + srow + 32 * p) * HW + n0 + scol + 32 * jj); \
  } while (0)
#define PQWRITE(BUF) do { \
    _Pragma("unroll") \
    for (int p = 0; p < 2; ++p) \
      _Pragma("unroll") \
      for (int jj = 0; jj < 4; ++jj) \
        *(uint4*)(&Xs[BUF][(srow + 32 * p) * 129 + scol + 32 * jj]) = sx[p][jj]; \
  } while (0)

  f32x4 acc[2][4];
#pragma unroll
  for (int rt = 0; rt < 2; ++rt)
#pragma unroll
    for (int ct = 0; ct < 4; ++ct) acc[rt][ct] = (f32x4){0.f, 0.f, 0.f, 0.f};

  PQLOAD(0); PQWRITE(0);
  __syncthreads();

  for (int t = 0; t < 8; ++t) {
    const int par = t & 1;
    if (t + 1 < 8) PQLOAD(t + 1);

#pragma unroll
    for (int kk = 0; kk < 2; ++kk) {
      bf16x8 af[2];
#pragma unroll
      for (int rt = 0; rt < 2; ++rt) {
        const float* col = &Xs[par][(kk * 32 + lg * 8) * 129 + wid * 32 + rt * 16 + lr];
        fragu fu;
#pragma unroll
        for (int j = 0; j < 4; ++j)
          fu.w[j] = cvtpk(col[(2 * j) * 129], col[(2 * j + 1) * 129]);
        af[rt] = fu.v;
      }
#pragma unroll
      for (int ct = 0; ct < 4; ++ct) {
        bf16x8 bf = *(const bf16x8*)(W + (size_t)(ct * 16 + lr) * CDIM + t * 64 + kk * 32 + lg * 8);
        acc[0][ct] = MFMA16(af[0], bf, acc[0][ct]);
        acc[1][ct] = MFMA16(af[1], bf, acc[1][ct]);
      }
    }

    if (t + 1 < 8) PQWRITE((t + 1) & 1);
    __syncthreads();
  }

#pragma unroll
  for (int rt = 0; rt < 2; ++rt)
#pragma unroll
    for (int ct = 0; ct < 4; ++ct)
#pragma unroll
      for (int r = 0; r < 4; ++r) {
        int i = n0 + wid * 32 + rt * 16 + lg * 4 + r;
        int j = ct * 16 + lr;
        D[(size_t)i * CI_ + j] = (u16)bfr((acc[rt][ct][r] + bias[j]) * alpha);
      }
}

// ---------------- fused V projection: V^T[c_out,m] = sum_c Wv[c_out,c] value[c,m] + bv ----------------
// value f32 [C,HW] transpose-staged (f32 [64c][64m +1pad], dbuf); Wv bf16 direct (hot).
// Block 256 = 4 waves; tile 128 c_out x 64 m. D bf16 [C,HW] per batch.
__global__ __launch_bounds__(256) void proj_v(
    const float* __restrict__ value, const u16* __restrict__ Wv,
    const float* __restrict__ bv, u16* __restrict__ Vo)
{
  __shared__ float Vsf[2][64 * 65];   // 2 x 16.6 KB

  const int bz = blockIdx.z;
  const float* X = value + (size_t)bz * CDIM * HW;
  u16* D = Vo + (size_t)bz * CDIM * HW;

  const int tid = threadIdx.x, wid = tid >> 6, lane = tid & 63;
  const int lr = lane & 15, lg = lane >> 4;
  const int i0 = blockIdx.x * 128 + wid * 32;   // c_out base (wave)
  const int j0 = blockIdx.y * 64;               // m base (block)

  const int srow = tid >> 3;            // 0..31
  const int scol = (tid & 7) * 4;       // + 32*jj, jj 0..1
  uint4 sv[2][2];

#define PVLOAD(T) do { \
    _Pragma("unroll") \
    for (int p = 0; p < 2; ++p) \
      _Pragma("unroll") \
      for (int jj = 0; jj < 2; ++jj) \
        sv[p][jj] = *(const uint4*)(X + (size_t)((T) * 64 + srow + 32 * p) * HW + j0 + scol + 32 * jj); \
  } while (0)
#define PVWRITE(BUF) do { \
    _Pragma("unroll") \
    for (int p = 0; p < 2; ++p) \
      _Pragma("unroll") \
      for (int jj = 0; jj < 2; ++jj) \
        *(uint4*)(&Vsf[BUF][(srow + 32 * p) * 65 + scol + 32 * jj]) = sv[p][jj]; \
  } while (0)

  f32x4 acc[2][4];
#pragma unroll
  for (int rt = 0; rt < 2; ++rt)
#pragma unroll
    for (int ct = 0; ct < 4; ++ct) acc[rt][ct] = (f32x4){0.f, 0.f, 0.f, 0.f};

  PVLOAD(0); PVWRITE(0);
  __syncthreads();

  for (int t = 0; t < 8; ++t) {
    const int par = t & 1;
    if (t + 1 < 8) PVLOAD(t + 1);

#pragma unroll
    for (int kk = 0; kk < 2; ++kk) {
      bf16x8 af[2];
#pragma unroll
      for (int rt = 0; rt < 2; ++rt)
        af[rt] = *(const bf16x8*)(Wv + (size_t)(i0 + rt * 16 + lr) * CDIM + t * 64 + kk * 32 + lg * 8);
#pragma unroll
      for (int ct = 0; ct < 4; ++ct) {
        const float* col = &Vsf[par][(kk * 32 + lg * 8) * 65 + ct * 16 + lr];
        fragu fu;
#pragma unroll
        for (int j = 0; j < 4; ++j)
          fu.w[j] = cvtpk(col[(2 * j) * 65], col[(2 * j + 1) * 65]);
        bf16x8 bf = fu.v;
        acc[0][ct] = MFMA16(af[0], bf, acc[0][ct]);
        acc[1][ct] = MFMA16(af[1], bf, acc[1][ct]);
      }
    }

    if (t + 1 < 8) PVWRITE((t + 1) & 1);
    __syncthreads();
  }

#pragma unroll
  for (int rt = 0; rt < 2; ++rt)
#pragma unroll
    for (int ct = 0; ct < 4; ++ct)
#pragma unroll
      for (int r = 0; r < 4; ++r) {
        int i = i0 + rt * 16 + lg * 4 + r;
        int j = j0 + ct * 16 + lr;
        D[(size_t)i * HW + j] = (u16)bfr(acc[rt][ct][r] + bv[i]);
      }
}

// ---------------- fused flash attention + gamma*attn + value ----------------
// R10 kernel, byte-identical (measured 236us: GLDS pre-swizzled staging + exp2 fold).
__global__ __launch_bounds__(256, 2) void flash_attn(
    const u16* __restrict__ Q, const u16* __restrict__ K, const u16* __restrict__ V,
    const float* __restrict__ value, const float* __restrict__ gammap, float* __restrict__ out)
{
  __shared__ u16 Ks[2][64 * 64];     // 2 x 8 KB   [m=64][ci=64], swizzled chunks
  __shared__ u16 Vs[2][128 * 64];    // 2 x 16 KB  [c=128][m=64], swizzled chunks

  const int b  = blockIdx.x & 7;
  const int rb = (blockIdx.x >> 3) & 15;
  const int ch = blockIdx.x >> 7;
  const int tid = threadIdx.x, wid = tid >> 6, lane = tid & 63;
  const int l31 = lane & 31, h = lane >> 5;

  const int n0 = rb * 256 + wid * 64;   // wave q-row base
  const int c0 = ch * 128;              // block c base

  const u16* Qb = Q + (size_t)b * HW * CI_;
  const u16* Kb = K + (size_t)b * HW * CI_;
  const u16* Vb = V + (size_t)b * CDIM * HW + (size_t)c0 * HW;

  // Q B-frags: col n = n0 + ng*32 + l31, k = kk*16 + h*8 + j
  bf16x8 qf[2][4];
#pragma unroll
  for (int ng = 0; ng < 2; ++ng)
#pragma unroll
    for (int kk = 0; kk < 4; ++kk)
      qf[ng][kk] = *(const bf16x8*)(Qb + (size_t)(n0 + ng * 32 + l31) * CI_ + kk * 16 + h * 8);

  f32x16 acc[2][4];
#pragma unroll
  for (int ng = 0; ng < 2; ++ng)
#pragma unroll
    for (int ct = 0; ct < 4; ++ct)
#pragma unroll
      for (int i = 0; i < 16; ++i) acc[ng][ct][i] = 0.f;
  float lp0 = 0.f, lp1 = 0.f;

  // ---- staging sources (pre-swizzled): lane -> (row = 8-block + lane>>3, chunk = lane&7)
  const int lrow = lane >> 3, lchk = lane & 7;
  const int swz = lchk ^ lrow;
  const u16* kcur = Kb + (size_t)(wid * 16 + lrow) * CI_ + swz * 8;
  const u16* vcur = Vb + (size_t)(wid * 32 + lrow) * HW + swz * 8;
  const int kofs = wid * 16 * 64, vofs = wid * 32 * 64;   // u16 LDS offsets

#define ISSUE(BUF) do { \
    GLDS16(kcur,              &Ks[BUF][kofs]); \
    GLDS16(kcur + 8 * CI_,    &Ks[BUF][kofs + 8 * 64]); \
    GLDS16(vcur,              &Vs[BUF][vofs]); \
    GLDS16(vcur + 8 * HW,     &Vs[BUF][vofs + 8 * 64]); \
    GLDS16(vcur + 16 * HW,    &Vs[BUF][vofs + 16 * 64]); \
    GLDS16(vcur + 24 * HW,    &Vs[BUF][vofs + 24 * 64]); \
  } while (0)

  ISSUE(0);
  __syncthreads();   // compiler-inserted vmcnt(0) drains the DMA

  for (int t = 0; t < NTIL; ++t) {
    const int par = t & 1;
    if (t + 1 < NTIL) {            // issue next-tile DMA; drains at this tile's end barrier
      kcur += MT * CI_;
      vcur += MT;
      ISSUE(par ^ 1);
    }

#pragma unroll
    for (int s = 0; s < 2; ++s) {  // m-strip of 32 within the 64-m tile
      // K A-frags: row m = s*32 + l31, chunk j = 2kk+h, swizzled by (m&7)==(l31&7)
      bf16x8 kf[4];
#pragma unroll
      for (int kk = 0; kk < 4; ++kk)
        kf[kk] = *(const bf16x8*)(&Ks[par][(s * 32 + l31) * 64 + (((2 * kk + h) ^ (l31 & 7)) << 3)]);

      bf16x8 pa[2][2];             // [ng][kk-local] PV B-frags for this strip
#pragma unroll
      for (int ng = 0; ng < 2; ++ng) {
        f32x16 st;
#pragma unroll
        for (int i = 0; i < 16; ++i) st[i] = 0.f;
#pragma unroll
        for (int kk = 0; kk < 4; ++kk)
          st = __builtin_amdgcn_mfma_f32_32x32x16_bf16(kf[kk], qf[ng][kk], st, 0, 0, 0);

        // P = exp2(S) (log2e pre-folded); row-sum partial
        float p[16]; float rs = 0.f;
#pragma unroll
        for (int r = 0; r < 16; ++r) { p[r] = hexp2(st[r]); rs += p[r]; }
        if (ng == 0) lp0 += rs; else lp1 += rs;

        // T12 pack: quads m(r) = (r&3) + 8*(r>>2) + 4h (within strip)
        u32 qa0 = cvtpk(p[0],  p[1]),  qa1 = cvtpk(p[2],  p[3]);   // m 4h+0..3
        u32 qb0 = cvtpk(p[4],  p[5]),  qb1 = cvtpk(p[6],  p[7]);   // m 8+4h+0..3
        u32 qc0 = cvtpk(p[8],  p[9]),  qc1 = cvtpk(p[10], p[11]);  // m 16+4h+0..3
        u32 qd0 = cvtpk(p[12], p[13]), qd1 = cvtpk(p[14], p[15]);  // m 24+4h+0..3
        asm("v_permlane32_swap_b32 %0, %1" : "+v"(qa0), "+v"(qb0));
        asm("v_permlane32_swap_b32 %0, %1" : "+v"(qa1), "+v"(qb1));
        asm("v_permlane32_swap_b32 %0, %1" : "+v"(qc0), "+v"(qd0));
        asm("v_permlane32_swap_b32 %0, %1" : "+v"(qc1), "+v"(qd1));
        fragu f0; f0.w[0] = qa0; f0.w[1] = qa1; f0.w[2] = qb0; f0.w[3] = qb1;
        pa[ng][0] = f0.v;
        fragu f1; f1.w[0] = qc0; f1.w[1] = qc1; f1.w[2] = qd0; f1.w[3] = qd1;
        pa[ng][1] = f1.v;
      }

      // PV partial for this strip: V chunk j = 4s + 2kkl + h, swizzled by (c&7)==(l31&7)
      __builtin_amdgcn_s_setprio(1);
#pragma unroll
      for (int ct = 0; ct < 4; ++ct)
#pragma unroll
        for (int kkl = 0; kkl < 2; ++kkl) {
          bf16x8 vf = *(const bf16x8*)(&Vs[par][(ct * 32 + l31) * 64 + (((4 * s + 2 * kkl + h) ^ (l31 & 7)) << 3)]);
          acc[0][ct] = __builtin_amdgcn_mfma_f32_32x32x16_bf16(vf, pa[0][kkl], acc[0][ct], 0, 0, 0);
          acc[1][ct] = __builtin_amdgcn_mfma_f32_32x32x16_bf16(vf, pa[1][kkl], acc[1][ct], 0, 0, 0);
        }
      __builtin_amdgcn_s_setprio(0);
    }

    __syncthreads();   // single barrier: drains next-tile DMA + fences dbuf parity
  }

  // ---- epilogue: per-wave LDS transpose so value/out stay coalesced ----
  __syncthreads();   // everyone done with Ks/Vs; reuse as scratch
  float* Tls = (float*)((char*)&Vs[0][0] + wid * 4352);  // 32c x 33n f32 = 4224B per wave
  const float g = gammap[0];
  const float ls0 = lp0 + __shfl_xor(lp0, 32);
  const float ls1 = lp1 + __shfl_xor(lp1, 32);
  const float ri0 = g / ls0, ri1 = g / ls1;   // gamma folded; lane's n = l31 (per ng)
  const size_t obase = (size_t)b * CDIM * HW;
#pragma unroll
  for (int ng = 0; ng < 2; ++ng) {
    const float ri = ng ? ri1 : ri0;
#pragma unroll
    for (int ct = 0; ct < 4; ++ct) {
#pragma unroll
      for (int r = 0; r < 16; ++r) {
        int cc = (r & 3) + 8 * (r >> 2) + 4 * h;
        Tls[cc * 33 + l31] = acc[ng][ct][r] * ri;
      }
#pragma unroll
      for (int p = 0; p < 16; ++p) {
        float v = Tls[l31 * 33 + 2 * p + h];
        int n = n0 + ng * 32 + 2 * p + h;
        int c = c0 + ct * 32 + l31;
        size_t idx = obase + (size_t)n * CDIM + c;
        out[idx] = v + value[idx];
      }
    }
  }
}

extern "C" void kernel_launch(void* const* d_in, const int* in_sizes, int n_in,
                              void* d_out, int out_size, void* d_ws, size_t ws_size,
                              hipStream_t stream) {
  const float* query = (const float*)d_in[0];
  const float* key   = (const float*)d_in[1];
  const float* value = (const float*)d_in[2];
  const float* Wq    = (const float*)d_in[3];
  const float* bq    = (const float*)d_in[4];
  const float* Wk    = (const float*)d_in[5];
  const float* bk    = (const float*)d_in[6];
  const float* Wv    = (const float*)d_in[7];
  const float* bv    = (const float*)d_in[8];
  const float* gamma = (const float*)d_in[9];

  char* ws = (char*)d_ws;
  u16* Qb  = (u16*)(ws + 33554432);    //  4,194,304 B  [B,HW,CI]
  u16* Kb  = (u16*)(ws + 37748736);    //  4,194,304 B  [B,HW,CI]
  u16* Vb  = (u16*)(ws + 41943040);    // 33,554,432 B  [B,C,HW] V^T
  u16* WQb = (u16*)(ws + 75497472);    //     65,536 B
  u16* WKb = (u16*)(ws + 75563008);    //     65,536 B
  u16* WVb = (u16*)(ws + 75628544);    //    524,288 B

  // 1) all three weight casts in one launch
  cast3<<<(CDIM * CDIM) / 256, 256, 0, stream>>>(Wq, Wk, Wv, WQb, WKb, WVb);

  // 2) Q and K projections with fused transpose+cast (z<8: Q, z>=8: K)
  proj_qk<<<dim3(HW / 128, 1, 16), 256, 0, stream>>>(
      query, key, WQb, WKb, bq, bk, Qb, Kb);

  // 3) V^T projection with fused transpose+cast -> [B, C, HW]
  proj_v<<<dim3(CDIM / 128, HW / 64, B_), 256, 0, stream>>>(
      value, WVb, bv, Vb);

  // 4) fused flash attention + epilogue
  flash_attn<<<512, 256, 0, stream>>>(Qb, Kb, Vb, value, gamma, (float*)d_out);
}